// Round 8
// baseline (265.895 us; speedup 1.0000x reference)
//
#include <hip/hip_runtime.h>
#include <math.h>

// R8: R4 (best, 103us) + surgical VALU/occupancy cuts. R7 lesson: shuffle-FFT
// trades LDS for ~3x dynamic instructions (bpermute+select) - dead end; FPB=8
// halves write granularity (WRITE 124MB). R4 model: VALUBusy 29% = ~5.7K
// inst/thread (f64 sincos preamble ~500, libm atan2f ~1K), runtime = 3.4x
// VALU-issue at 3 blocks/CU -> cut instructions + add a block:
//  1) fp32 cospif/sinpif twiddles (exact args j/128, j/256) - no f64.
//  2) fast_atan2 (deg-11 minimax, err 2.4e-6 << 1.05 thr; R5-R7 validated).
//  3) xs LDS dropped: phase-1 reads global directly (L2, 3.4x intra-block
//     reuse); patch reads global (identical values, identical fmaf order).
//     LDS 45.5->37.7KB -> 4 blocks/CU. a[16] dies before epilogue: no spill.
//  4) SLOT swizzle 16j+((k+j)&15) on Z: phase-1 store was 8-way bank-
//     conflicted (32*th = 0 mod 32 collapsed th); now all phases <=2-way.
//     Sets stay th-partitioned -> in-place phase-2 still race-free.
//  5) m204 bijective XCD swizzle (nwg=101: q=12,r=5): adjacent t-chunks
//     share 128B out-lines -> co-locate on one XCD for write merge.
// Numerics contract unchanged: sequential-k fmaf branch-cut patch (R3),
// same emit order, same thresholds class.

#define BATCH 16
#define NSAMP 160000
#define NF 257
#define NT 1603
#define KLEN 400
#define INC 100
#define PADL 300
#define EPSF 1.1920928955078125e-7f
#define TAU 1e-2f

#define FPB 16                            // frames per block
#define ZSTR 258                          // complex stride per frame row
#define NTB ((NT + FPB - 1) / FPB)        // 101
#define SLOT(j, k) (16 * (j) + (((k) + (j)) & 15))

__device__ __forceinline__ float2 cmul(float2 a, float2 b) {
  return make_float2(a.x * b.x - a.y * b.y, a.x * b.y + a.y * b.x);
}

// 16-point DIF FFT in registers; output a[r] = F[brev4(r)].
__device__ __forceinline__ void fft16_dif(float2* a) {
  const float C1 = 0.92387953251128674f;   // cos(pi/8)
  const float S1 = 0.38268343236508978f;   // sin(pi/8)
  const float R2 = 0.70710678118654752f;   // sqrt(2)/2
  {                                        // span 8, tw = w16^j
    const float2 W[8] = {{1.f, 0.f},  {C1, -S1},  {R2, -R2},  {S1, -C1},
                         {0.f, -1.f}, {-S1, -C1}, {-R2, -R2}, {-C1, -S1}};
    #pragma unroll
    for (int j = 0; j < 8; ++j) {
      float2 u = a[j], v = a[j + 8];
      a[j] = make_float2(u.x + v.x, u.y + v.y);
      float2 d = make_float2(u.x - v.x, u.y - v.y);
      a[j + 8] = cmul(d, W[j]);
    }
  }
  {                                        // span 4, tw = w8^j
    const float2 W[4] = {{1.f, 0.f}, {R2, -R2}, {0.f, -1.f}, {-R2, -R2}};
    #pragma unroll
    for (int h = 0; h < 16; h += 8)
      #pragma unroll
      for (int j = 0; j < 4; ++j) {
        float2 u = a[h + j], v = a[h + j + 4];
        a[h + j] = make_float2(u.x + v.x, u.y + v.y);
        float2 d = make_float2(u.x - v.x, u.y - v.y);
        a[h + j + 4] = cmul(d, W[j]);
      }
  }
  #pragma unroll
  for (int q = 0; q < 16; q += 4) {        // span 2, tw = {1, -i}
    float2 u0 = a[q], v0 = a[q + 2];
    a[q] = make_float2(u0.x + v0.x, u0.y + v0.y);
    a[q + 2] = make_float2(u0.x - v0.x, u0.y - v0.y);
    float2 u1 = a[q + 1], v1 = a[q + 3];
    a[q + 1] = make_float2(u1.x + v1.x, u1.y + v1.y);
    float2 d = make_float2(u1.x - v1.x, u1.y - v1.y);
    a[q + 3] = make_float2(d.y, -d.x);     // *(-i)
  }
  #pragma unroll
  for (int q = 0; q < 16; q += 2) {        // span 1
    float2 u = a[q], v = a[q + 1];
    a[q] = make_float2(u.x + v.x, u.y + v.y);
    a[q + 1] = make_float2(u.x - v.x, u.y - v.y);
  }
}

// atan2 via deg-11 odd minimax on [0,1] (max err ~2.4e-6 rad; thr = 1.05).
__device__ __forceinline__ float fast_atan2(float y, float x) {
  float ax = fabsf(x), ay = fabsf(y);
  float mx = fmaxf(ax, ay), mn = fminf(ax, ay);
  float t = mn * __builtin_amdgcn_rcpf(fmaxf(mx, 1e-37f));
  float s = t * t;
  float p = fmaf(s, -0.01172120f, 0.05265332f);
  p = fmaf(s, p, -0.11643287f);
  p = fmaf(s, p, 0.19354346f);
  p = fmaf(s, p, -0.33262347f);
  p = fmaf(s, p, 0.99997726f);
  float r = t * p;
  if (ay > ax) r = 1.57079632679489662f - r;
  if (x < 0.f) r = 3.14159265358979324f - r;
  return (y < 0.f) ? -r : r;
}

// mag/phase emit; branch-cut patch recomputes via bit-exact v5 order from
// GLOBAL x (values identical to the old xs copy: 0-padded outside [0,NSAMP)).
__device__ __forceinline__ void emit_fp(float rr, float ii, int ff,
                                        const float* __restrict__ w,
                                        const float* __restrict__ x,
                                        long xb, int gb,
                                        float* __restrict__ out,
                                        long o, long plane) {
  float ie = ii + EPSF, re = rr + EPSF;
  if (fabsf(ie) < TAU && re < TAU) {       // cold path, ~2 pts/block
    const float* wr = w + (long)ff * KLEN;
    const float* wi = w + (long)(257 + ff) * KLEN;
    float r2 = 0.f, i2 = 0.f;
    for (int k = 0; k < KLEN; ++k) {       // sequential k (v5 rounding class)
      int g = gb + k;
      float xv = (g >= 0 && g < NSAMP) ? x[xb + g] : 0.f;
      r2 = fmaf(wr[k], xv, r2);
      i2 = fmaf(wi[k], xv, i2);
    }
    rr = r2; ii = i2;
  }
  out[o] = sqrtf(fmaxf(rr * rr + ii * ii, EPSF));
  out[o + plane] = fast_atan2(ii + EPSF, rr + EPSF);
}

__global__ __launch_bounds__(256, 4)
void stft_fft8(const float* __restrict__ x, const float* __restrict__ w,
               float* __restrict__ out) {
  __shared__ float2 Z[FPB * ZSTR];          // 33024 B
  __shared__ float2 tw[132];                // 1056 B: e^{-2pi i p/512}
  __shared__ float2 tw256[256];             // 2048 B: e^{-2pi i j/256}
  __shared__ __align__(16) float win[KLEN]; // 1600 B  (total ~37.7 KB)

  const int tid = threadIdx.x;
  const int b = blockIdx.y;
  const int tl = tid & 15;                  // frame
  const int th = tid >> 4;                  // worker: n2 (ph1) = k1 (ph2)

  // m204 bijective XCD swizzle over 101 t-chunks (q=12, r=5)
  const int u = blockIdx.x;
  const int xcd = u & 7;
  const int tb = ((xcd < 5) ? xcd * 13 : 65 + (xcd - 5) * 12) + (u >> 3);
  const int t0 = tb * FPB;

  // ---- stage win + fp32 twiddle tables (exact args: j/128, j/256) ----
  const long xb = (long)b * NSAMP;
  if (tid < KLEN / 4) {                     // W row 0 = fp32(hamming) exactly
    *(float4*)&win[4 * tid] = *(const float4*)(w + 4 * tid);
  }
  {
    float a = (float)tid * (1.0f / 128.0f);
    tw256[tid] = make_float2(cospif(a), -sinpif(a));
  }
  if (tid < 132) {
    float a = (float)tid * (1.0f / 256.0f);
    tw[tid] = make_float2(cospif(a), -sinpif(a));
  }
  __syncthreads();

  // ---- phase 1: windowed GLOBAL load z[32*n1+2*th] -> register FFT ----
  float2 a[16];
  const int gb1 = (t0 + tl) * INC - PADL;   // this frame's x base
  #pragma unroll
  for (int n1 = 0; n1 < 13; ++n1) {
    int n = 32 * n1 + 2 * th;
    float2 zv = make_float2(0.f, 0.f);
    if (n < KLEN) {                         // excludes n1=12, th>=8
      int g = gb1 + n;                      // g even; g<NSAMP => g+1<NSAMP
      if (g >= 0 && g < NSAMP) {
        float2 xv = *(const float2*)(x + xb + g);
        float2 wv = *(const float2*)&win[n];
        zv = make_float2(xv.x * wv.x, xv.y * wv.y);
      }
    }
    a[n1] = zv;
  }
  a[13] = a[14] = a[15] = make_float2(0.f, 0.f);

  fft16_dif(a);                             // a[r] = F1[th][brev4(r)]

  static const int BR[16] = {0, 8, 4, 12, 2, 10, 6, 14,
                             1, 9, 5, 13, 3, 11, 7, 15};
  float2* Zf = Z + tl * ZSTR;
  #pragma unroll
  for (int r = 0; r < 16; ++r) {            // x w256^{th*k1}, SLOT store
    const int k1 = BR[r];
    float2 v = (k1 == 0) ? a[r] : cmul(a[r], tw256[th * k1]);
    Zf[SLOT(th, k1)] = v;                   // <=2-way banks (th in index now)
  }
  __syncthreads();

  // ---- phase 2: SLOT column read -> register FFT over n2 (th-partitioned) --
  {
    float2 g[16];
    #pragma unroll
    for (int n2 = 0; n2 < 16; ++n2) g[n2] = Zf[SLOT(n2, th)];
    fft16_dif(g);                           // g[r] = Z[16*brev4(r) + th]
    #pragma unroll
    for (int r = 0; r < 16; ++r) {
      const int k2 = BR[r];
      Zf[SLOT(k2, th)] = g[r];              // same th-partitioned set: no race
    }
  }
  __syncthreads();

  // ---- fused rFFT-unpack + mag/phase + coalesced store ----
  const long plane = (long)BATCH * NF * NT;
  const long pb = (long)b * NF * NT;
  for (int r = 0; r < 9; ++r) {
    int tau = r * 256 + tid;
    if (tau < FPB * 129) {
      int t16 = tau & 15;
      int p = tau >> 4;                     // 0..128
      float2* Zt = Z + t16 * ZSTR;
      int q = (256 - p) & 255;
      float2 z0 = Zt[SLOT(p >> 4, p & 15)];
      float2 z1 = Zt[SLOT(q >> 4, q & 15)];
      float2 ze = make_float2(0.5f * (z0.x + z1.x), 0.5f * (z0.y - z1.y));
      float2 zo = make_float2(0.5f * (z0.y + z1.y), 0.5f * (z1.x - z0.x));
      float2 T = tw[p];
      float2 tz = cmul(zo, T);
      float2 ya = make_float2(ze.x + tz.x, ze.y + tz.y);          // Y[p]
      float2 yb = make_float2(ze.x - tz.x, tz.y - ze.y);          // Y[256-p]
      int tt = t0 + t16;
      if (tt < NT) {
        int gbt = tt * INC - PADL;
        emit_fp(ya.x, ya.y, p, w, x, xb, gbt, out,
                pb + (long)p * NT + tt, plane);
        if (p == 0) {
          emit_fp(yb.x, 0.f, 256, w, x, xb, gbt, out,
                  pb + (long)256 * NT + tt, plane);
        } else {
          emit_fp(yb.x, yb.y, 256 - p, w, x, xb, gbt, out,
                  pb + (long)(256 - p) * NT + tt, plane);
        }
      }
    }
  }
}

extern "C" void kernel_launch(void* const* d_in, const int* in_sizes, int n_in,
                              void* d_out, int out_size, void* d_ws, size_t ws_size,
                              hipStream_t stream) {
  const float* x = (const float*)d_in[0];   // (16, 160000) fp32
  const float* w = (const float*)d_in[1];   // (514, 1, 400) fp32
  float* out = (float*)d_out;

  dim3 grid(NTB, BATCH);                    // 101 x 16 = 1616 blocks
  stft_fft8<<<grid, dim3(256), 0, stream>>>(x, w, out);
}

// Round 9
// 254.010 us; speedup vs baseline: 1.0468x; 1.0468x over previous
//
#include <hip/hip_runtime.h>
#include <math.h>

// R9: R4's exact structure (best: 103us) + only the individually-validated
// deltas. R8 post-mortem: swapping the xs LDS stage for strided global
// phase-1 loads was the poison (VGPR 52 pathology, serialized 500cy loads,
// VALU time UP); but it VALIDATED fp32 cospif/sinpif twiddles + global-x
// patch reads (absmax 0.125 unchanged) and the XCD swizzle (WRITE 74->64MB).
// Changes vs R4 (hot paths untouched):
//  1) fast_atan2 (deg-11 minimax, err 2.4e-6 << 1.05 thr) + fp32 twiddles:
//     cuts ~1.5K of ~5.7K VALU inst/thread.
//  2) Branch-cut patch reads GLOBAL x (bit-identical values; R8-validated)
//     -> xs/win dead after phase-1 -> Z ALIASES xs/win (union + one extra
//     barrier between a[]-loads and transpose store). LDS 45.5 -> 35.3KB
//     -> 4 blocks/CU (+33% latency hiding). a[16] still dies pre-epilogue.
//  3) m204 bijective XCD swizzle (nwg=101: q=12,r=5) for out-line merging.
// Numerics contract unchanged: sequential-k fmaf patch order (R3), same
// emit order/structure as R4.

#define BATCH 16
#define NSAMP 160000
#define NF 257
#define NT 1603
#define KLEN 400
#define INC 100
#define PADL 300
#define EPSF 1.1920928955078125e-7f
#define TAU 1e-2f

#define FPB 16                            // frames per block
#define ZSTR 258                          // complex stride per frame row
#define XSPAN ((FPB - 1) * INC + KLEN)    // 1900
#define NTB ((NT + FPB - 1) / FPB)        // 101
#define UNIF (FPB * ZSTR * 2)             // 8256 floats = 33024 B union

__device__ __forceinline__ float2 cmul(float2 a, float2 b) {
  return make_float2(a.x * b.x - a.y * b.y, a.x * b.y + a.y * b.x);
}

// 16-point DIF FFT in registers; output a[r] = F[brev4(r)].
__device__ __forceinline__ void fft16_dif(float2* a) {
  const float C1 = 0.92387953251128674f;   // cos(pi/8)
  const float S1 = 0.38268343236508978f;   // sin(pi/8)
  const float R2 = 0.70710678118654752f;   // sqrt(2)/2
  {                                        // span 8, tw = w16^j
    const float2 W[8] = {{1.f, 0.f},  {C1, -S1},  {R2, -R2},  {S1, -C1},
                         {0.f, -1.f}, {-S1, -C1}, {-R2, -R2}, {-C1, -S1}};
    #pragma unroll
    for (int j = 0; j < 8; ++j) {
      float2 u = a[j], v = a[j + 8];
      a[j] = make_float2(u.x + v.x, u.y + v.y);
      float2 d = make_float2(u.x - v.x, u.y - v.y);
      a[j + 8] = cmul(d, W[j]);
    }
  }
  {                                        // span 4, tw = w8^j
    const float2 W[4] = {{1.f, 0.f}, {R2, -R2}, {0.f, -1.f}, {-R2, -R2}};
    #pragma unroll
    for (int h = 0; h < 16; h += 8)
      #pragma unroll
      for (int j = 0; j < 4; ++j) {
        float2 u = a[h + j], v = a[h + j + 4];
        a[h + j] = make_float2(u.x + v.x, u.y + v.y);
        float2 d = make_float2(u.x - v.x, u.y - v.y);
        a[h + j + 4] = cmul(d, W[j]);
      }
  }
  #pragma unroll
  for (int q = 0; q < 16; q += 4) {        // span 2, tw = {1, -i}
    float2 u0 = a[q], v0 = a[q + 2];
    a[q] = make_float2(u0.x + v0.x, u0.y + v0.y);
    a[q + 2] = make_float2(u0.x - v0.x, u0.y - v0.y);
    float2 u1 = a[q + 1], v1 = a[q + 3];
    a[q + 1] = make_float2(u1.x + v1.x, u1.y + v1.y);
    float2 d = make_float2(u1.x - v1.x, u1.y - v1.y);
    a[q + 3] = make_float2(d.y, -d.x);     // *(-i)
  }
  #pragma unroll
  for (int q = 0; q < 16; q += 2) {        // span 1
    float2 u = a[q], v = a[q + 1];
    a[q] = make_float2(u.x + v.x, u.y + v.y);
    a[q + 1] = make_float2(u.x - v.x, u.y - v.y);
  }
}

// atan2 via deg-11 odd minimax on [0,1] (max err ~2.4e-6 rad; thr = 1.05).
__device__ __forceinline__ float fast_atan2(float y, float x) {
  float ax = fabsf(x), ay = fabsf(y);
  float mx = fmaxf(ax, ay), mn = fminf(ax, ay);
  float t = mn * __builtin_amdgcn_rcpf(fmaxf(mx, 1e-37f));
  float s = t * t;
  float p = fmaf(s, -0.01172120f, 0.05265332f);
  p = fmaf(s, p, -0.11643287f);
  p = fmaf(s, p, 0.19354346f);
  p = fmaf(s, p, -0.33262347f);
  p = fmaf(s, p, 0.99997726f);
  float r = t * p;
  if (ay > ax) r = 1.57079632679489662f - r;
  if (x < 0.f) r = 3.14159265358979324f - r;
  return (y < 0.f) ? -r : r;
}

// mag/phase emit; branch-cut patch recomputes with the bit-exact v5
// sequential-fmaf order from GLOBAL x (identical values to the xs copy).
__device__ __forceinline__ void emit_fp(float rr, float ii, int ff,
                                        const float* __restrict__ w,
                                        const float* __restrict__ x,
                                        long xb, int gb,
                                        float* __restrict__ out,
                                        long o, long plane) {
  float ie = ii + EPSF, re = rr + EPSF;
  if (fabsf(ie) < TAU && re < TAU) {       // cold path, ~2 pts/block
    const float* wr = w + (long)ff * KLEN;
    const float* wi = w + (long)(257 + ff) * KLEN;
    float r2 = 0.f, i2 = 0.f;
    for (int k = 0; k < KLEN; ++k) {       // sequential k (v5 rounding class)
      int g = gb + k;
      float xv = (g >= 0 && g < NSAMP) ? x[xb + g] : 0.f;
      r2 = fmaf(wr[k], xv, r2);
      i2 = fmaf(wi[k], xv, i2);
    }
    rr = r2; ii = i2;
  }
  out[o] = sqrtf(fmaxf(rr * rr + ii * ii, EPSF));
  out[o + plane] = fast_atan2(ii + EPSF, rr + EPSF);
}

__global__ __launch_bounds__(256, 4)
void stft_fft9(const float* __restrict__ x, const float* __restrict__ w,
               float* __restrict__ out) {
  __shared__ __align__(16) float uni[UNIF]; // 33024 B: xs+win, then Z
  __shared__ float2 tw[132];                // 1056 B: e^{-2pi i p/512}
  __shared__ float2 tw256[256];             // 2048 B: e^{-2pi i j/256}
  float* xs = uni;                          // [1900]
  float* win = uni + 1904;                  // [400], 16B aligned
  float2* Z = (float2*)uni;                 // [16][258] overlays xs/win

  const int tid = threadIdx.x;
  const int b = blockIdx.y;
  const int tl = tid & 15;                  // frame
  const int th = tid >> 4;                  // worker: n2 (ph1) = k1 (ph2)

  // m204 bijective XCD swizzle over 101 t-chunks (q=12, r=5)
  const int u = blockIdx.x;
  const int xcd = u & 7;
  const int tb = ((xcd < 5) ? xcd * 13 : 65 + (xcd - 5) * 12) + (u >> 3);
  const int t0 = tb * FPB;

  // ---- stage xs (vectorized, zero-padded), win, fp32 twiddle tables ----
  const long xb = (long)b * NSAMP;
  const int base = t0 * INC - PADL;
  for (int r = 0; r < 2; ++r) {
    int i4 = r * 256 + tid;
    if (4 * i4 < XSPAN) {
      int g = base + 4 * i4;
      float4 v;
      if (g >= 0 && g + 3 < NSAMP) {
        v = *(const float4*)(x + xb + g);
      } else {
        v.x = (g + 0 >= 0 && g + 0 < NSAMP) ? x[xb + g + 0] : 0.f;
        v.y = (g + 1 >= 0 && g + 1 < NSAMP) ? x[xb + g + 1] : 0.f;
        v.z = (g + 2 >= 0 && g + 2 < NSAMP) ? x[xb + g + 2] : 0.f;
        v.w = (g + 3 >= 0 && g + 3 < NSAMP) ? x[xb + g + 3] : 0.f;
      }
      *(float4*)&xs[4 * i4] = v;
    }
  }
  if (tid < KLEN / 4) {                     // W row 0 = fp32(hamming) exactly
    *(float4*)&win[4 * tid] = *(const float4*)(w + 4 * tid);
  }
  {
    float aa = (float)tid * (1.0f / 128.0f);
    tw256[tid] = make_float2(cospif(aa), -sinpif(aa));
  }
  if (tid < 132) {
    float aa = (float)tid * (1.0f / 256.0f);
    tw[tid] = make_float2(cospif(aa), -sinpif(aa));
  }
  __syncthreads();

  // ---- phase 1: windowed LDS load z[32*n1+2*th] into registers ----
  float2 a[16];
  const float* xf = &xs[tl * INC];
  #pragma unroll
  for (int n1 = 0; n1 < 12; ++n1) {         // n = 32*n1+2*th <= 382 < 400
    int n = 32 * n1 + 2 * th;
    float2 xv = *(const float2*)&xf[n];
    float2 wv = *(const float2*)&win[n];
    a[n1] = make_float2(xv.x * wv.x, xv.y * wv.y);
  }
  {
    int n = 384 + 2 * th;                   // n1 = 12: valid iff th <= 7
    if (n < KLEN) {
      float2 xv = *(const float2*)&xf[n];
      float2 wv = *(const float2*)&win[n];
      a[12] = make_float2(xv.x * wv.x, xv.y * wv.y);
    } else {
      a[12] = make_float2(0.f, 0.f);
    }
  }
  a[13] = a[14] = a[15] = make_float2(0.f, 0.f);   // y[n]=0, n>=416

  __syncthreads();                          // all xs/win reads done: Z may alias

  fft16_dif(a);                             // a[r] = F1[th][brev4(r)]

  static const int BR[16] = {0, 8, 4, 12, 2, 10, 6, 14,
                             1, 9, 5, 13, 3, 11, 7, 15};
  float2* Zf = Z + tl * ZSTR;
  #pragma unroll
  for (int r = 0; r < 16; ++r) {            // x w256^{th*k1}, transpose-store
    const int k1 = BR[r];
    float2 v = (k1 == 0) ? a[r] : cmul(a[r], tw256[th * k1]);
    Zf[th * 16 + k1] = v;                   // R4 layout (conflicts ~2us, ok)
  }
  __syncthreads();

  // ---- phase 2: column read (private per thread) -> register FFT over n2 ----
  {
    float2 g[16];
    #pragma unroll
    for (int n2 = 0; n2 < 16; ++n2) g[n2] = Zf[n2 * 16 + th];
    fft16_dif(g);                           // g[r] = Z[16*brev4(r) + th]
    #pragma unroll
    for (int r = 0; r < 16; ++r) {
      const int k2 = BR[r];
      Zf[16 * k2 + th] = g[r];              // natural-order spectrum
    }
  }
  __syncthreads();

  // ---- fused rFFT-unpack + mag/phase + coalesced store ----
  const long plane = (long)BATCH * NF * NT;
  const long pb = (long)b * NF * NT;
  for (int r = 0; r < 9; ++r) {
    int tau = r * 256 + tid;
    if (tau < FPB * 129) {
      int t16 = tau & 15;
      int p = tau >> 4;                     // 0..128
      float2* Zt = Z + t16 * ZSTR;
      float2 z0 = Zt[p];
      float2 z1 = Zt[(256 - p) & 255];
      float2 ze = make_float2(0.5f * (z0.x + z1.x), 0.5f * (z0.y - z1.y));
      float2 zo = make_float2(0.5f * (z0.y + z1.y), 0.5f * (z1.x - z0.x));
      float2 T = tw[p];
      float2 tz = cmul(zo, T);
      float2 ya = make_float2(ze.x + tz.x, ze.y + tz.y);          // Y[p]
      float2 yb = make_float2(ze.x - tz.x, tz.y - ze.y);          // Y[256-p]
      int tt = t0 + t16;
      if (tt < NT) {
        int gbt = tt * INC - PADL;
        emit_fp(ya.x, ya.y, p, w, x, xb, gbt, out,
                pb + (long)p * NT + tt, plane);
        if (p == 0) {
          emit_fp(yb.x, 0.f, 256, w, x, xb, gbt, out,
                  pb + (long)256 * NT + tt, plane);
        } else {
          emit_fp(yb.x, yb.y, 256 - p, w, x, xb, gbt, out,
                  pb + (long)(256 - p) * NT + tt, plane);
        }
      }
    }
  }
}

extern "C" void kernel_launch(void* const* d_in, const int* in_sizes, int n_in,
                              void* d_out, int out_size, void* d_ws, size_t ws_size,
                              hipStream_t stream) {
  const float* x = (const float*)d_in[0];   // (16, 160000) fp32
  const float* w = (const float*)d_in[1];   // (514, 1, 400) fp32
  float* out = (float*)d_out;

  dim3 grid(NTB, BATCH);                    // 101 x 16 = 1616 blocks
  stft_fft9<<<grid, dim3(256), 0, stream>>>(x, w, out);
}

// Round 10
// 156.564 us; speedup vs baseline: 1.6983x; 1.6224x over previous
//
#include <hip/hip_runtime.h>
#include <math.h>

// R10: R4 structure (best: 103us) + 4 blocks/CU WITHOUT touching the patch.
// R9 post-mortem: R8's real poison was patch-from-GLOBAL-x (400 bounds-
// checked dependent ~300cy loads per event, ~1.5 events/block -> huge wave-
// serial tails; R9 kept it and stayed at 200us despite LDS phase-1). So:
//  - patch reads LDS xs again (R4's exact fast path, 103us-validated);
//  - 4 blocks/CU reached by deleting ALL tables instead of xs:
//      win, tw256, tw computed on the fly via cospif/sinpif (identical
//      expressions to the R8-validated tables; window ~1ulp vs W row 0 is
//      safe: flip-risk points have |i+eps| < FFT-err << TAU -> patched).
//    LDS = Z 33024 + xs 7600 = 40624B <= 40960 (=160K/4) -> 4 blocks/CU.
//  - SLOT swizzle (R8-validated numerics): with ZSTR=258 all Z phases are
//    <=2-way banked vs R4's 8-way transpose store (1.14M conflict cycles).
//  - fast_atan2 (R5-R9 validated) and m204 XCD swizzle (WRITE 74->64MB).
// Numerics contract: sequential-k fmaf patch (R3) from LDS xs + global w.

#define BATCH 16
#define NSAMP 160000
#define NF 257
#define NT 1603
#define KLEN 400
#define INC 100
#define PADL 300
#define EPSF 1.1920928955078125e-7f
#define TAU 1e-2f

#define FPB 16                            // frames per block
#define ZSTR 258                          // complex stride per frame row
#define XSPAN ((FPB - 1) * INC + KLEN)    // 1900
#define NTB ((NT + FPB - 1) / FPB)        // 101
#define SLOT(j, k) (16 * (j) + (((k) + (j)) & 15))

__device__ __forceinline__ float2 cmul(float2 a, float2 b) {
  return make_float2(a.x * b.x - a.y * b.y, a.x * b.y + a.y * b.x);
}

// 16-point DIF FFT in registers; output a[r] = F[brev4(r)].
__device__ __forceinline__ void fft16_dif(float2* a) {
  const float C1 = 0.92387953251128674f;   // cos(pi/8)
  const float S1 = 0.38268343236508978f;   // sin(pi/8)
  const float R2 = 0.70710678118654752f;   // sqrt(2)/2
  {                                        // span 8, tw = w16^j
    const float2 W[8] = {{1.f, 0.f},  {C1, -S1},  {R2, -R2},  {S1, -C1},
                         {0.f, -1.f}, {-S1, -C1}, {-R2, -R2}, {-C1, -S1}};
    #pragma unroll
    for (int j = 0; j < 8; ++j) {
      float2 u = a[j], v = a[j + 8];
      a[j] = make_float2(u.x + v.x, u.y + v.y);
      float2 d = make_float2(u.x - v.x, u.y - v.y);
      a[j + 8] = cmul(d, W[j]);
    }
  }
  {                                        // span 4, tw = w8^j
    const float2 W[4] = {{1.f, 0.f}, {R2, -R2}, {0.f, -1.f}, {-R2, -R2}};
    #pragma unroll
    for (int h = 0; h < 16; h += 8)
      #pragma unroll
      for (int j = 0; j < 4; ++j) {
        float2 u = a[h + j], v = a[h + j + 4];
        a[h + j] = make_float2(u.x + v.x, u.y + v.y);
        float2 d = make_float2(u.x - v.x, u.y - v.y);
        a[h + j + 4] = cmul(d, W[j]);
      }
  }
  #pragma unroll
  for (int q = 0; q < 16; q += 4) {        // span 2, tw = {1, -i}
    float2 u0 = a[q], v0 = a[q + 2];
    a[q] = make_float2(u0.x + v0.x, u0.y + v0.y);
    a[q + 2] = make_float2(u0.x - v0.x, u0.y - v0.y);
    float2 u1 = a[q + 1], v1 = a[q + 3];
    a[q + 1] = make_float2(u1.x + v1.x, u1.y + v1.y);
    float2 d = make_float2(u1.x - v1.x, u1.y - v1.y);
    a[q + 3] = make_float2(d.y, -d.x);     // *(-i)
  }
  #pragma unroll
  for (int q = 0; q < 16; q += 2) {        // span 1
    float2 u = a[q], v = a[q + 1];
    a[q] = make_float2(u.x + v.x, u.y + v.y);
    a[q + 1] = make_float2(u.x - v.x, u.y - v.y);
  }
}

// atan2 via deg-11 odd minimax on [0,1] (max err ~2.4e-6 rad; thr = 1.05).
__device__ __forceinline__ float fast_atan2(float y, float x) {
  float ax = fabsf(x), ay = fabsf(y);
  float mx = fmaxf(ax, ay), mn = fminf(ax, ay);
  float t = mn * __builtin_amdgcn_rcpf(fmaxf(mx, 1e-37f));
  float s = t * t;
  float p = fmaf(s, -0.01172120f, 0.05265332f);
  p = fmaf(s, p, -0.11643287f);
  p = fmaf(s, p, 0.19354346f);
  p = fmaf(s, p, -0.33262347f);
  p = fmaf(s, p, 0.99997726f);
  float r = t * p;
  if (ay > ax) r = 1.57079632679489662f - r;
  if (x < 0.f) r = 3.14159265358979324f - r;
  return (y < 0.f) ? -r : r;
}

// mag/phase emit; branch-cut patch: bit-exact v5 sequential-fmaf from LDS xs
// (R4's exact cold path) + exact W rows from global.
__device__ __forceinline__ void emit_fp(float rr, float ii, int ff,
                                        const float* __restrict__ w,
                                        const float* xf,
                                        float* __restrict__ out,
                                        long o, long plane) {
  float ie = ii + EPSF, re = rr + EPSF;
  if (fabsf(ie) < TAU && re < TAU) {       // cold path, ~2 pts/block
    const float* wr = w + (long)ff * KLEN;
    const float* wi = w + (long)(257 + ff) * KLEN;
    float r2 = 0.f, i2 = 0.f;
    for (int k = 0; k < KLEN; ++k) {       // sequential k (v5 rounding class)
      float xv = xf[k];
      r2 = fmaf(wr[k], xv, r2);
      i2 = fmaf(wi[k], xv, i2);
    }
    rr = r2; ii = i2;
  }
  out[o] = sqrtf(fmaxf(rr * rr + ii * ii, EPSF));
  out[o + plane] = fast_atan2(ii + EPSF, rr + EPSF);
}

__global__ __launch_bounds__(256, 4)
void stft_fft10(const float* __restrict__ x, const float* __restrict__ w,
                float* __restrict__ out) {
  __shared__ float2 Z[FPB * ZSTR];          // 33024 B
  __shared__ __align__(16) float xs[XSPAN]; // 7600 B   (total 40624 <= 40960)

  const int tid = threadIdx.x;
  const int b = blockIdx.y;
  const int tl = tid & 15;                  // frame
  const int th = tid >> 4;                  // worker: n2 (ph1) = k1 (ph2)

  // m204 bijective XCD swizzle over 101 t-chunks (q=12, r=5)
  const int u = blockIdx.x;
  const int xcd = u & 7;
  const int tb = ((xcd < 5) ? xcd * 13 : 65 + (xcd - 5) * 12) + (u >> 3);
  const int t0 = tb * FPB;

  // ---- stage xs (vectorized, zero-padded) ----
  const long xb = (long)b * NSAMP;
  const int base = t0 * INC - PADL;
  for (int r = 0; r < 2; ++r) {
    int i4 = r * 256 + tid;
    if (4 * i4 < XSPAN) {
      int g = base + 4 * i4;
      float4 v;
      if (g >= 0 && g + 3 < NSAMP) {
        v = *(const float4*)(x + xb + g);
      } else {
        v.x = (g + 0 >= 0 && g + 0 < NSAMP) ? x[xb + g + 0] : 0.f;
        v.y = (g + 1 >= 0 && g + 1 < NSAMP) ? x[xb + g + 1] : 0.f;
        v.z = (g + 2 >= 0 && g + 2 < NSAMP) ? x[xb + g + 2] : 0.f;
        v.w = (g + 3 >= 0 && g + 3 < NSAMP) ? x[xb + g + 3] : 0.f;
      }
      *(float4*)&xs[4 * i4] = v;
    }
  }
  __syncthreads();

  // ---- phase 1: windowed LDS load (window on the fly) -> register FFT ----
  float2 a[16];
  const float* xf = &xs[tl * INC];
  #pragma unroll
  for (int n1 = 0; n1 < 12; ++n1) {         // n = 32*n1+2*th <= 382 < 400
    int n = 32 * n1 + 2 * th;
    float2 xv = *(const float2*)&xf[n];
    float w0 = fmaf(-0.46f, cospif((float)n * 0.005f), 0.54f);
    float w1 = fmaf(-0.46f, cospif((float)(n + 1) * 0.005f), 0.54f);
    a[n1] = make_float2(xv.x * w0, xv.y * w1);
  }
  {
    int n = 384 + 2 * th;                   // n1 = 12: valid iff th <= 7
    if (n < KLEN) {
      float2 xv = *(const float2*)&xf[n];
      float w0 = fmaf(-0.46f, cospif((float)n * 0.005f), 0.54f);
      float w1 = fmaf(-0.46f, cospif((float)(n + 1) * 0.005f), 0.54f);
      a[12] = make_float2(xv.x * w0, xv.y * w1);
    } else {
      a[12] = make_float2(0.f, 0.f);
    }
  }
  a[13] = a[14] = a[15] = make_float2(0.f, 0.f);   // y[n]=0, n>=416

  fft16_dif(a);                             // a[r] = F1[th][brev4(r)]

  static const int BR[16] = {0, 8, 4, 12, 2, 10, 6, 14,
                             1, 9, 5, 13, 3, 11, 7, 15};
  float2* Zf = Z + tl * ZSTR;
  #pragma unroll
  for (int r = 0; r < 16; ++r) {            // x w256^{th*k1} on the fly
    const int k1 = BR[r];
    float2 v;
    if (k1 == 0) {
      v = a[r];
    } else {
      float aa = (float)(th * k1) * (1.0f / 128.0f);
      float2 t256 = make_float2(cospif(aa), -sinpif(aa));
      v = cmul(a[r], t256);
    }
    Zf[SLOT(th, k1)] = v;                   // <=2-way banks (SLOT + stride 258)
  }
  __syncthreads();

  // ---- phase 2: SLOT column read -> register FFT over n2 (th-partitioned) --
  {
    float2 g[16];
    #pragma unroll
    for (int n2 = 0; n2 < 16; ++n2) g[n2] = Zf[SLOT(n2, th)];
    fft16_dif(g);                           // g[r] = Z[16*brev4(r) + th]
    #pragma unroll
    for (int r = 0; r < 16; ++r) {
      const int k2 = BR[r];
      Zf[SLOT(k2, th)] = g[r];              // same th-partitioned set: no race
    }
  }
  __syncthreads();

  // ---- fused rFFT-unpack + mag/phase + coalesced store ----
  const long plane = (long)BATCH * NF * NT;
  const long pb = (long)b * NF * NT;
  for (int r = 0; r < 9; ++r) {
    int tau = r * 256 + tid;
    if (tau < FPB * 129) {
      int t16 = tau & 15;
      int p = tau >> 4;                     // 0..128
      float2* Zt = Z + t16 * ZSTR;
      int q = (256 - p) & 255;
      float2 z0 = Zt[SLOT(p >> 4, p & 15)];
      float2 z1 = Zt[SLOT(q >> 4, q & 15)];
      float2 ze = make_float2(0.5f * (z0.x + z1.x), 0.5f * (z0.y - z1.y));
      float2 zo = make_float2(0.5f * (z0.y + z1.y), 0.5f * (z1.x - z0.x));
      float ta = (float)p * (1.0f / 256.0f);
      float2 T = make_float2(cospif(ta), -sinpif(ta));
      float2 tz = cmul(zo, T);
      float2 ya = make_float2(ze.x + tz.x, ze.y + tz.y);          // Y[p]
      float2 yb = make_float2(ze.x - tz.x, tz.y - ze.y);          // Y[256-p]
      int tt = t0 + t16;
      if (tt < NT) {
        const float* xfr = &xs[t16 * INC];
        emit_fp(ya.x, ya.y, p, w, xfr, out, pb + (long)p * NT + tt, plane);
        if (p == 0) {
          emit_fp(yb.x, 0.f, 256, w, xfr, out,
                  pb + (long)256 * NT + tt, plane);
        } else {
          emit_fp(yb.x, yb.y, 256 - p, w, xfr, out,
                  pb + (long)(256 - p) * NT + tt, plane);
        }
      }
    }
  }
}

extern "C" void kernel_launch(void* const* d_in, const int* in_sizes, int n_in,
                              void* d_out, int out_size, void* d_ws, size_t ws_size,
                              hipStream_t stream) {
  const float* x = (const float*)d_in[0];   // (16, 160000) fp32
  const float* w = (const float*)d_in[1];   // (514, 1, 400) fp32
  float* out = (float*)d_out;

  dim3 grid(NTB, BATCH);                    // 101 x 16 = 1616 blocks
  stft_fft10<<<grid, dim3(256), 0, stream>>>(x, w, out);
}